// Round 13
// baseline (75.722 us; speedup 1.0000x reference)
//
#include <hip/hip_runtime.h>
#include <hip/hip_bf16.h>

#define PAD_IDX 0
#define SEQ_L 64
#define ROWS_PER_BLOCK 128
#define THREADS 256
// per-row LDS stride in int4 units: 16 data + 1 pad (16B) to spread banks
#define ROW_STRIDE4 17

typedef int   v4i __attribute__((ext_vector_type(4)));
typedef uint  v4u __attribute__((ext_vector_type(4)));
typedef uint  v2u __attribute__((ext_vector_type(2)));
typedef float v4f __attribute__((ext_vector_type(4)));

#if defined(__has_builtin)
#if __has_builtin(__builtin_amdgcn_raw_buffer_load_b128) && __has_builtin(__builtin_amdgcn_make_buffer_rsrc)
#define USE_BUFLOAD 1
#endif
#endif

__device__ __forceinline__ float bf16_lo(unsigned int w) {
    return __uint_as_float(w << 16);
}
__device__ __forceinline__ float bf16_hi(unsigned int w) {
    return __uint_as_float(w & 0xffff0000u);
}

// ---- Pass 1: convert fp32 table -> packed bf16 table in workspace (L2-resident).
__global__ __launch_bounds__(256) void convert_bf16_kernel(
    const float* __restrict__ emb, ushort* __restrict__ tab, int n /* elements */)
{
    int i4 = (blockIdx.x * 256 + threadIdx.x) * 4;
    if (i4 + 3 < n) {
        float4 v = *reinterpret_cast<const float4*>(emb + i4);
        ushort4 o;
        o.x = __bfloat16_as_ushort(__float2bfloat16(v.x));
        o.y = __bfloat16_as_ushort(__float2bfloat16(v.y));
        o.z = __bfloat16_as_ushort(__float2bfloat16(v.z));
        o.w = __bfloat16_as_ushort(__float2bfloat16(v.w));
        *reinterpret_cast<ushort4*>(tab + i4) = o;
    } else if (i4 < n) {
        for (int k = i4; k < n; ++k)
            tab[k] = __bfloat16_as_ushort(__float2bfloat16(emb[k]));
    }
}

// ---- Pass 2: 2 lanes/row x 16B buffer_load gathers (half the quads per row).
__global__ __launch_bounds__(THREADS, 6) void visit_encoder_bf16v9_kernel(
    const int* __restrict__ code_ids,
    const ushort* __restrict__ tab,  // bf16 table, row = 32B
    float* __restrict__ out,
    int B, int n_codes4)
{
    __shared__ v4i lcodes[ROWS_PER_BLOCK * ROW_STRIDE4];  // 34816 B

    const int t = threadIdx.x;
    const int block_row0 = blockIdx.x * ROWS_PER_BLOCK;

    // Stage 128 rows x 64 codes = 2048 int4; coalesced cached loads.
    const v4i* src4 = reinterpret_cast<const v4i*>(code_ids);
    const int base4 = blockIdx.x * (ROWS_PER_BLOCK * SEQ_L / 4);
    #pragma unroll
    for (int k = 0; k < 8; ++k) {
        int j = t + THREADS * k;                 // 0..2047
        int gj = base4 + j;
        if (gj >= n_codes4) gj = n_codes4 - 1;   // tail clamp (ids stay valid)
        v4i v = src4[gj];
        lcodes[(j >> 4) * ROW_STRIDE4 + (j & 15)] = v;
    }
    __syncthreads();

    const int r  = t >> 1;     // 0..127 row within block
    const int d8 = t & 1;      // half-row: dims 8*d8 .. 8*d8+7

#ifdef USE_BUFLOAD
    __amdgpu_buffer_rsrc_t rsrc =
        __builtin_amdgcn_make_buffer_rsrc((void*)tab, (short)0,
                                          0xFFFFFFFFu, 0x00020000);
    const int d8off = d8 * 16;           // byte offset within 32B row
#define GATHER(c) __builtin_amdgcn_raw_buffer_load_b128(rsrc, (c) * 32 + d8off, 0, 1)
#else
    const v4u* tbase = reinterpret_cast<const v4u*>(tab) + d8;
#define GATHER(c) (tbase[(size_t)(c) * 2])
#endif

    float acc[8] = {0.f,0.f,0.f,0.f,0.f,0.f,0.f,0.f};
    int cnt = 0;

    // 8 batches of 8 codes; 8 x 16B gathers in flight per batch.
    #pragma unroll
    for (int b = 0; b < 8; ++b) {
        v4i c0 = lcodes[r * ROW_STRIDE4 + b * 2 + 0];
        v4i c1 = lcodes[r * ROW_STRIDE4 + b * 2 + 1];
        int cc[8] = {c0.x, c0.y, c0.z, c0.w, c1.x, c1.y, c1.z, c1.w};
        v4u e[8];
        #pragma unroll
        for (int u = 0; u < 8; ++u) {
            e[u] = GATHER(cc[u]);
        }
        #pragma unroll
        for (int u = 0; u < 8; ++u) {
            float m = (cc[u] != PAD_IDX) ? 1.0f : 0.0f;
            v4u w = e[u];
            acc[0] = fmaf(bf16_lo(w.x), m, acc[0]);
            acc[1] = fmaf(bf16_hi(w.x), m, acc[1]);
            acc[2] = fmaf(bf16_lo(w.y), m, acc[2]);
            acc[3] = fmaf(bf16_hi(w.y), m, acc[3]);
            acc[4] = fmaf(bf16_lo(w.z), m, acc[4]);
            acc[5] = fmaf(bf16_hi(w.z), m, acc[5]);
            acc[6] = fmaf(bf16_lo(w.w), m, acc[6]);
            acc[7] = fmaf(bf16_hi(w.w), m, acc[7]);
            cnt += (cc[u] != PAD_IDX);
        }
    }
#undef GATHER

    const int row = block_row0 + r;
    if (row < B) {
        float inv = 1.0f / fmaxf((float)cnt, 1.0f);
        v4f o0, o1;
        o0.x = acc[0]*inv; o0.y = acc[1]*inv; o0.z = acc[2]*inv; o0.w = acc[3]*inv;
        o1.x = acc[4]*inv; o1.y = acc[5]*inv; o1.z = acc[6]*inv; o1.w = acc[7]*inv;
        v4f* op = reinterpret_cast<v4f*>(out + (size_t)row * 16 + d8 * 8);
        __builtin_nontemporal_store(o0, op);
        __builtin_nontemporal_store(o1, op + 1);
    }
}

// ---- Fallback: direct fp32 gather (proven R2 kernel) if ws too small.
__global__ __launch_bounds__(256) void visit_encoder_f32_kernel(
    const int* __restrict__ code_ids,
    const float* __restrict__ emb,
    float* __restrict__ out,
    int B, int n_codes4)
{
    __shared__ int4 lcodes[64 * 17];
    const int t = threadIdx.x;
    const int block_row0 = blockIdx.x * 64;
    const int4* src4 = reinterpret_cast<const int4*>(code_ids);
    const int base4 = blockIdx.x * (64 * SEQ_L / 4);
    #pragma unroll
    for (int k = 0; k < 4; ++k) {
        int j = t + 256 * k;
        int gj = base4 + j;
        if (gj >= n_codes4) gj = n_codes4 - 1;
        lcodes[(j >> 4) * 17 + (j & 15)] = src4[gj];
    }
    __syncthreads();
    const int r  = t >> 2;
    const int d4 = t & 3;
    const float4* ebase = reinterpret_cast<const float4*>(emb) + d4;
    float4 acc = make_float4(0.f, 0.f, 0.f, 0.f);
    int cnt = 0;
    #pragma unroll
    for (int l4 = 0; l4 < 16; l4 += 2) {
        int4 ca = lcodes[r * 17 + l4];
        int4 cb = lcodes[r * 17 + l4 + 1];
        int csx[8] = {ca.x, ca.y, ca.z, ca.w, cb.x, cb.y, cb.z, cb.w};
        float4 e[8];
        #pragma unroll
        for (int u = 0; u < 8; ++u) e[u] = ebase[(size_t)csx[u] * 4];
        #pragma unroll
        for (int u = 0; u < 8; ++u) {
            float m = (csx[u] != PAD_IDX) ? 1.0f : 0.0f;
            acc.x = fmaf(e[u].x, m, acc.x);
            acc.y = fmaf(e[u].y, m, acc.y);
            acc.z = fmaf(e[u].z, m, acc.z);
            acc.w = fmaf(e[u].w, m, acc.w);
            cnt += (csx[u] != PAD_IDX);
        }
    }
    const int row = block_row0 + r;
    if (row < B) {
        float inv = 1.0f / fmaxf((float)cnt, 1.0f);
        float4 o;
        o.x = acc.x * inv; o.y = acc.y * inv; o.z = acc.z * inv; o.w = acc.w * inv;
        reinterpret_cast<float4*>(out)[(size_t)row * 4 + d4] = o;
    }
}

extern "C" void kernel_launch(void* const* d_in, const int* in_sizes, int n_in,
                              void* d_out, int out_size, void* d_ws, size_t ws_size,
                              hipStream_t stream) {
    const int*   code_ids = (const int*)d_in[0];
    const float* emb      = (const float*)d_in[1];
    float*       out      = (float*)d_out;

    const int total_codes = in_sizes[0];        // B * L
    const int B = total_codes / SEQ_L;
    const int n_codes4 = total_codes / 4;
    const int emb_elems = in_sizes[1];          // NUM_CODES * DIM

    const size_t tab_bytes = (size_t)emb_elems * sizeof(ushort);
    if (ws_size >= tab_bytes) {
        ushort* tab = (ushort*)d_ws;
        int n4 = (emb_elems + 3) / 4;
        convert_bf16_kernel<<<dim3((n4 + 255) / 256), dim3(256), 0, stream>>>(
            emb, tab, emb_elems);
        const int grid = (B + ROWS_PER_BLOCK - 1) / ROWS_PER_BLOCK;
        visit_encoder_bf16v9_kernel<<<dim3(grid), dim3(THREADS), 0, stream>>>(
            code_ids, tab, out, B, n_codes4);
    } else {
        const int grid = (B + 63) / 64;
        visit_encoder_f32_kernel<<<dim3(grid), dim3(256), 0, stream>>>(
            code_ids, emb, out, B, n_codes4);
    }
}